// Round 1
// baseline (653.703 us; speedup 1.0000x reference)
//
#include <hip/hip_runtime.h>

// Coo2Cel: periodic minimum-image pair displacements / squared distances / mask.
// B=2, N=4096, dense [B,N,N] outputs. Write-bandwidth-bound (~671 MB out).
// Numerics deliberately mirror the numpy f32 reference (no FMA contraction) so
// the sod < rc^2 boundary decisions match bit-for-bit on this (diagonal-cell)
// input.

constexpr int N_ATOMS = 4096;
constexpr int N_BATCH = 2;
constexpr float RC2 = 36.0f; // rc = 6.0

// ---------------- kernel 1: frac = pos @ inv(cel) ----------------
__global__ __launch_bounds__(256) void frac_kernel(const float* __restrict__ pos,
                                                   const float* __restrict__ cel,
                                                   float* __restrict__ frac) {
    int idx = blockIdx.x * blockDim.x + threadIdx.x; // 0 .. B*N-1
    if (idx >= N_BATCH * N_ATOMS) return;
    int b = idx >> 12; // / 4096
    const float* c = cel + b * 9;
    float a00 = c[0], a01 = c[1], a02 = c[2];
    float a10 = c[3], a11 = c[4], a12 = c[5];
    float a20 = c[6], a21 = c[7], a22 = c[8];
    // Cofactors (adjugate). For a diagonal cell every off-diagonal product is an
    // exact 0.0f, so this matches LAPACK's inverse bit-for-bit on this input.
    float cof00 = __fsub_rn(__fmul_rn(a11, a22), __fmul_rn(a12, a21));
    float cof01 = __fsub_rn(__fmul_rn(a12, a20), __fmul_rn(a10, a22));
    float cof02 = __fsub_rn(__fmul_rn(a10, a21), __fmul_rn(a11, a20));
    float cof10 = __fsub_rn(__fmul_rn(a02, a21), __fmul_rn(a01, a22));
    float cof11 = __fsub_rn(__fmul_rn(a00, a22), __fmul_rn(a02, a20));
    float cof12 = __fsub_rn(__fmul_rn(a01, a20), __fmul_rn(a00, a21));
    float cof20 = __fsub_rn(__fmul_rn(a01, a12), __fmul_rn(a02, a11));
    float cof21 = __fsub_rn(__fmul_rn(a02, a10), __fmul_rn(a00, a12));
    float cof22 = __fsub_rn(__fmul_rn(a00, a11), __fmul_rn(a01, a10));
    float det = __fadd_rn(__fadd_rn(__fmul_rn(a00, cof00), __fmul_rn(a01, cof01)),
                          __fmul_rn(a02, cof02));
    // inv[i][j] = cof[j][i] / det
    float i00 = __fdiv_rn(cof00, det), i01 = __fdiv_rn(cof10, det), i02 = __fdiv_rn(cof20, det);
    float i10 = __fdiv_rn(cof01, det), i11 = __fdiv_rn(cof11, det), i12 = __fdiv_rn(cof21, det);
    float i20 = __fdiv_rn(cof02, det), i21 = __fdiv_rn(cof12, det), i22 = __fdiv_rn(cof22, det);
    float p0 = pos[idx * 3 + 0], p1 = pos[idx * 3 + 1], p2 = pos[idx * 3 + 2];
    // Ordered sum ((p0*i + p1*i) + p2*i), no FMA contraction.
    frac[idx * 3 + 0] = __fadd_rn(__fadd_rn(__fmul_rn(p0, i00), __fmul_rn(p1, i10)), __fmul_rn(p2, i20));
    frac[idx * 3 + 1] = __fadd_rn(__fadd_rn(__fmul_rn(p0, i01), __fmul_rn(p1, i11)), __fmul_rn(p2, i21));
    frac[idx * 3 + 2] = __fadd_rn(__fadd_rn(__fmul_rn(p0, i02), __fmul_rn(p1, i12)), __fmul_rn(p2, i22));
}

// ---------------- kernel 2: all pairs ----------------
// Grid: B * N * (N/1024) blocks of 256 threads; each thread handles 4 consecutive j.
__global__ __launch_bounds__(256) void pairs_kernel(const float* __restrict__ frac,
                                                    const float* __restrict__ cel,
                                                    const int* __restrict__ pbc,
                                                    const int* __restrict__ ent,
                                                    float* __restrict__ out) {
    constexpr int N = N_ATOMS;
    int bid = blockIdx.x;
    int jt = bid & 3;              // which 1024-wide j tile
    int i  = (bid >> 2) & (N - 1); // row
    int b  = bid >> 14;            // batch (4096*4 = 2^14 blocks per batch)
    int j0 = (jt << 10) + ((int)threadIdx.x << 2);

    const float* c = cel + b * 9;
    float c00 = c[0], c01 = c[1], c02 = c[2];
    float c10 = c[3], c11 = c[4], c12 = c[5];
    float c20 = c[6], c21 = c[7], c22 = c[8];
    float px = pbc[b * 3 + 0] ? 1.0f : 0.0f;
    float py = pbc[b * 3 + 1] ? 1.0f : 0.0f;
    float pz = pbc[b * 3 + 2] ? 1.0f : 0.0f;

    const float* fi = frac + ((size_t)(b * N + i)) * 3;
    float fix = fi[0], fiy = fi[1], fiz = fi[2];
    bool enti = ent[b * N + i] != 0;

    // 4 consecutive atoms' frac: 12 floats = 3 aligned float4 loads.
    const float4* fj4 = reinterpret_cast<const float4*>(frac + ((size_t)(b * N + j0)) * 3);
    float4 q0 = fj4[0], q1 = fj4[1], q2 = fj4[2];
    float fjx[4] = {q0.x, q0.w, q1.z, q2.y};
    float fjy[4] = {q0.y, q1.x, q1.w, q2.z};
    float fjz[4] = {q0.z, q1.y, q2.x, q2.w};
    int4 ej4 = *reinterpret_cast<const int4*>(ent + b * N + j0);
    int ej[4] = {ej4.x, ej4.y, ej4.z, ej4.w};

    float vbuf[12];
    float sodv[4];
    float mskv[4];
#pragma unroll
    for (int t = 0; t < 4; ++t) {
        int j = j0 + t;
        // dfrac = frac[j] - frac[i], minimum image (round half-to-even like np.round)
        float dx = __fsub_rn(fjx[t], fix);
        float dy = __fsub_rn(fjy[t], fiy);
        float dz = __fsub_rn(fjz[t], fiz);
        dx = __fsub_rn(dx, __fmul_rn(rintf(dx), px));
        dy = __fsub_rn(dy, __fmul_rn(rintf(dy), py));
        dz = __fsub_rn(dz, __fmul_rn(rintf(dz), pz));
        // vec = dfrac @ cel, ordered sum, no FMA
        float vx = __fadd_rn(__fadd_rn(__fmul_rn(dx, c00), __fmul_rn(dy, c10)), __fmul_rn(dz, c20));
        float vy = __fadd_rn(__fadd_rn(__fmul_rn(dx, c01), __fmul_rn(dy, c11)), __fmul_rn(dz, c21));
        float vz = __fadd_rn(__fadd_rn(__fmul_rn(dx, c02), __fmul_rn(dy, c12)), __fmul_rn(dz, c22));
        float sod = __fadd_rn(__fadd_rn(__fmul_rn(vx, vx), __fmul_rn(vy, vy)), __fmul_rn(vz, vz));
        bool m = (j != i) && enti && (ej[t] != 0) && (sod < RC2);
        vbuf[t * 3 + 0] = m ? vx : 0.0f;
        vbuf[t * 3 + 1] = m ? vy : 0.0f;
        vbuf[t * 3 + 2] = m ? vz : 0.0f;
        sodv[t] = m ? sod : 0.0f;
        mskv[t] = m ? 1.0f : 0.0f;
    }

    size_t pbase = (size_t)b * N * N + (size_t)i * N + (size_t)j0;
    // vec: [B,N,N,3] at out[0 ..)
    float4* vout = reinterpret_cast<float4*>(out + pbase * 3);
    vout[0] = make_float4(vbuf[0], vbuf[1], vbuf[2], vbuf[3]);
    vout[1] = make_float4(vbuf[4], vbuf[5], vbuf[6], vbuf[7]);
    vout[2] = make_float4(vbuf[8], vbuf[9], vbuf[10], vbuf[11]);
    // sod: [B,N,N] after vec
    constexpr size_t VEC_TOTAL = (size_t)N_BATCH * N * N * 3;
    *reinterpret_cast<float4*>(out + VEC_TOTAL + pbase) =
        make_float4(sodv[0], sodv[1], sodv[2], sodv[3]);
    // mask: [B,N,N] after sod (bool -> 1.0/0.0)
    constexpr size_t SOD_TOTAL = (size_t)N_BATCH * N * N;
    *reinterpret_cast<float4*>(out + VEC_TOTAL + SOD_TOTAL + pbase) =
        make_float4(mskv[0], mskv[1], mskv[2], mskv[3]);
}

extern "C" void kernel_launch(void* const* d_in, const int* in_sizes, int n_in,
                              void* d_out, int out_size, void* d_ws, size_t ws_size,
                              hipStream_t stream) {
    const float* pos = (const float*)d_in[0]; // [B,N,3]
    const float* cel = (const float*)d_in[1]; // [B,3,3]
    const int* pbc   = (const int*)d_in[2];   // [B,3]
    const int* ent   = (const int*)d_in[3];   // [B,N]
    float* out = (float*)d_out;
    float* frac = (float*)d_ws; // B*N*3 floats = 96 KB

    int natoms_total = N_BATCH * N_ATOMS;
    frac_kernel<<<(natoms_total + 255) / 256, 256, 0, stream>>>(pos, cel, frac);

    int nblocks = N_BATCH * N_ATOMS * (N_ATOMS / 1024); // 32768
    pairs_kernel<<<nblocks, 256, 0, stream>>>(frac, cel, pbc, ent, out);
}

// Round 3
// 647.244 us; speedup vs baseline: 1.0100x; 1.0100x over previous
//
#include <hip/hip_runtime.h>

// Coo2Cel: periodic minimum-image pair displacements / squared distances / mask.
// B=2, N=4096, dense [B,N,N] outputs. Write-bandwidth-bound (~671 MB out).
// Numerics mirror the numpy f32 reference (ordered sums, no FMA contraction,
// rintf == np.round half-to-even) so sod < rc^2 boundary decisions match.
//
// R3: same as R2 plan (LDS-transposed coalesced vec stores + nontemporal
// streaming stores) but using a native clang vector type for the nontemporal
// builtins -- HIP's float4 is a class and __builtin_nontemporal_store rejects
// it.

typedef float v4f __attribute__((ext_vector_type(4)));

constexpr int N_ATOMS = 4096;
constexpr int N_BATCH = 2;
constexpr float RC2 = 36.0f; // rc = 6.0

// ---------------- kernel 1: frac = pos @ inv(cel) ----------------
__global__ __launch_bounds__(256) void frac_kernel(const float* __restrict__ pos,
                                                   const float* __restrict__ cel,
                                                   float* __restrict__ frac) {
    int idx = blockIdx.x * blockDim.x + threadIdx.x; // 0 .. B*N-1
    if (idx >= N_BATCH * N_ATOMS) return;
    int b = idx >> 12; // / 4096
    const float* c = cel + b * 9;
    float a00 = c[0], a01 = c[1], a02 = c[2];
    float a10 = c[3], a11 = c[4], a12 = c[5];
    float a20 = c[6], a21 = c[7], a22 = c[8];
    // Cofactors (adjugate). For a diagonal cell every off-diagonal product is an
    // exact 0.0f, so this matches LAPACK's inverse bit-for-bit on this input.
    float cof00 = __fsub_rn(__fmul_rn(a11, a22), __fmul_rn(a12, a21));
    float cof01 = __fsub_rn(__fmul_rn(a12, a20), __fmul_rn(a10, a22));
    float cof02 = __fsub_rn(__fmul_rn(a10, a21), __fmul_rn(a11, a20));
    float cof10 = __fsub_rn(__fmul_rn(a02, a21), __fmul_rn(a01, a22));
    float cof11 = __fsub_rn(__fmul_rn(a00, a22), __fmul_rn(a02, a20));
    float cof12 = __fsub_rn(__fmul_rn(a01, a20), __fmul_rn(a00, a21));
    float cof20 = __fsub_rn(__fmul_rn(a01, a12), __fmul_rn(a02, a11));
    float cof21 = __fsub_rn(__fmul_rn(a02, a10), __fmul_rn(a00, a12));
    float cof22 = __fsub_rn(__fmul_rn(a00, a11), __fmul_rn(a01, a10));
    float det = __fadd_rn(__fadd_rn(__fmul_rn(a00, cof00), __fmul_rn(a01, cof01)),
                          __fmul_rn(a02, cof02));
    // inv[i][j] = cof[j][i] / det
    float i00 = __fdiv_rn(cof00, det), i01 = __fdiv_rn(cof10, det), i02 = __fdiv_rn(cof20, det);
    float i10 = __fdiv_rn(cof01, det), i11 = __fdiv_rn(cof11, det), i12 = __fdiv_rn(cof21, det);
    float i20 = __fdiv_rn(cof02, det), i21 = __fdiv_rn(cof12, det), i22 = __fdiv_rn(cof22, det);
    float p0 = pos[idx * 3 + 0], p1 = pos[idx * 3 + 1], p2 = pos[idx * 3 + 2];
    // Ordered sum ((p0*i + p1*i) + p2*i), no FMA contraction.
    frac[idx * 3 + 0] = __fadd_rn(__fadd_rn(__fmul_rn(p0, i00), __fmul_rn(p1, i10)), __fmul_rn(p2, i20));
    frac[idx * 3 + 1] = __fadd_rn(__fadd_rn(__fmul_rn(p0, i01), __fmul_rn(p1, i11)), __fmul_rn(p2, i21));
    frac[idx * 3 + 2] = __fadd_rn(__fadd_rn(__fmul_rn(p0, i02), __fmul_rn(p1, i12)), __fmul_rn(p2, i22));
}

// ---------------- kernel 2: all pairs ----------------
// Grid: B * N * (N/1024) blocks of 256 threads; each thread handles 4 consecutive j.
__global__ __launch_bounds__(256) void pairs_kernel(const float* __restrict__ frac,
                                                    const float* __restrict__ cel,
                                                    const int* __restrict__ pbc,
                                                    const int* __restrict__ ent,
                                                    float* __restrict__ out) {
    constexpr int N = N_ATOMS;
    __shared__ float lds_vec[3072]; // 1024 j * 3 comps = 12 KB

    int bid = blockIdx.x;
    int jt = bid & 3;              // which 1024-wide j tile
    int i  = (bid >> 2) & (N - 1); // row
    int b  = bid >> 14;            // batch (4096*4 = 2^14 blocks per batch)
    int t  = (int)threadIdx.x;
    int jblk = jt << 10;           // block's first j
    int j0 = jblk + (t << 2);      // thread's first j

    const float* c = cel + b * 9;
    float c00 = c[0], c01 = c[1], c02 = c[2];
    float c10 = c[3], c11 = c[4], c12 = c[5];
    float c20 = c[6], c21 = c[7], c22 = c[8];
    float px = pbc[b * 3 + 0] ? 1.0f : 0.0f;
    float py = pbc[b * 3 + 1] ? 1.0f : 0.0f;
    float pz = pbc[b * 3 + 2] ? 1.0f : 0.0f;

    const float* fi = frac + ((size_t)(b * N + i)) * 3;
    float fix = fi[0], fiy = fi[1], fiz = fi[2];
    bool enti = ent[b * N + i] != 0;

    // 4 consecutive atoms' frac: 12 floats = 3 aligned 16B loads.
    const v4f* fj4 = reinterpret_cast<const v4f*>(frac + ((size_t)(b * N + j0)) * 3);
    v4f q0 = fj4[0], q1 = fj4[1], q2 = fj4[2];
    float fjx[4] = {q0.x, q0.w, q1.z, q2.y};
    float fjy[4] = {q0.y, q1.x, q1.w, q2.z};
    float fjz[4] = {q0.z, q1.y, q2.x, q2.w};
    int4 ej4 = *reinterpret_cast<const int4*>(ent + b * N + j0);
    int ej[4] = {ej4.x, ej4.y, ej4.z, ej4.w};

    float vbuf[12];
    v4f sodv, mskv;
#pragma unroll
    for (int u = 0; u < 4; ++u) {
        int j = j0 + u;
        // dfrac = frac[j] - frac[i], minimum image (round half-to-even like np.round)
        float dx = __fsub_rn(fjx[u], fix);
        float dy = __fsub_rn(fjy[u], fiy);
        float dz = __fsub_rn(fjz[u], fiz);
        dx = __fsub_rn(dx, __fmul_rn(rintf(dx), px));
        dy = __fsub_rn(dy, __fmul_rn(rintf(dy), py));
        dz = __fsub_rn(dz, __fmul_rn(rintf(dz), pz));
        // vec = dfrac @ cel, ordered sum, no FMA
        float vx = __fadd_rn(__fadd_rn(__fmul_rn(dx, c00), __fmul_rn(dy, c10)), __fmul_rn(dz, c20));
        float vy = __fadd_rn(__fadd_rn(__fmul_rn(dx, c01), __fmul_rn(dy, c11)), __fmul_rn(dz, c21));
        float vz = __fadd_rn(__fadd_rn(__fmul_rn(dx, c02), __fmul_rn(dy, c12)), __fmul_rn(dz, c22));
        float sod = __fadd_rn(__fadd_rn(__fmul_rn(vx, vx), __fmul_rn(vy, vy)), __fmul_rn(vz, vz));
        bool m = (j != i) && enti && (ej[u] != 0) && (sod < RC2);
        vbuf[u * 3 + 0] = m ? vx : 0.0f;
        vbuf[u * 3 + 1] = m ? vy : 0.0f;
        vbuf[u * 3 + 2] = m ? vz : 0.0f;
        sodv[u] = m ? sod : 0.0f;
        mskv[u] = m ? 1.0f : 0.0f;
    }

    size_t blockpbase = (size_t)b * N * N + (size_t)i * N + (size_t)jblk;
    constexpr size_t VEC_TOTAL = (size_t)N_BATCH * N * N * 3;
    constexpr size_t SOD_TOTAL = (size_t)N_BATCH * N * N;

    // sod / mask: already perfectly coalesced (16B/lane, contiguous).
    v4f* sout = reinterpret_cast<v4f*>(out + VEC_TOTAL + blockpbase) + t;
    v4f* mout = reinterpret_cast<v4f*>(out + VEC_TOTAL + SOD_TOTAL + blockpbase) + t;
    __builtin_nontemporal_store(sodv, sout);
    __builtin_nontemporal_store(mskv, mout);

    // vec: transpose through LDS so global stores are fully coalesced.
    // Write floats [12t, 12t+12): banks 12t%32 cover all 32 banks once per 8
    // lanes (gcd(12,32)=4, b128 spans 4) -> conflict-free.
    v4f* lv_w = reinterpret_cast<v4f*>(lds_vec + t * 12);
    lv_w[0] = (v4f){vbuf[0], vbuf[1], vbuf[2], vbuf[3]};
    lv_w[1] = (v4f){vbuf[4], vbuf[5], vbuf[6], vbuf[7]};
    lv_w[2] = (v4f){vbuf[8], vbuf[9], vbuf[10], vbuf[11]};
    __syncthreads();
    // Read 16B at t + 256k (stride 1024 floats = 0 mod 32 banks -> same bank
    // pattern as a linear b128 read, conflict-free), store coalesced.
    const v4f* lv_r = reinterpret_cast<const v4f*>(lds_vec);
    v4f* vout = reinterpret_cast<v4f*>(out + blockpbase * 3);
    __builtin_nontemporal_store(lv_r[t], vout + t);
    __builtin_nontemporal_store(lv_r[t + 256], vout + t + 256);
    __builtin_nontemporal_store(lv_r[t + 512], vout + t + 512);
}

extern "C" void kernel_launch(void* const* d_in, const int* in_sizes, int n_in,
                              void* d_out, int out_size, void* d_ws, size_t ws_size,
                              hipStream_t stream) {
    const float* pos = (const float*)d_in[0]; // [B,N,3]
    const float* cel = (const float*)d_in[1]; // [B,3,3]
    const int* pbc   = (const int*)d_in[2];   // [B,3]
    const int* ent   = (const int*)d_in[3];   // [B,N]
    float* out = (float*)d_out;
    float* frac = (float*)d_ws; // B*N*3 floats = 96 KB

    int natoms_total = N_BATCH * N_ATOMS;
    frac_kernel<<<(natoms_total + 255) / 256, 256, 0, stream>>>(pos, cel, frac);

    int nblocks = N_BATCH * N_ATOMS * (N_ATOMS / 1024); // 32768
    pairs_kernel<<<nblocks, 256, 0, stream>>>(frac, cel, pbc, ent, out);
}